// Round 5
// baseline (172.024 us; speedup 1.0000x reference)
//
#include <hip/hip_runtime.h>

#define OUT_F 11008
#define IN_F  4096
#define PKW   2048   // int32 words per weight row (each word holds 1 byte = 2 nibbles)
#define BLKQ  128

typedef __attribute__((ext_vector_type(8))) short          s16x8;
typedef __attribute__((ext_vector_type(8))) unsigned short u16x8;
typedef __attribute__((ext_vector_type(4))) float          f32x4;
typedef __attribute__((ext_vector_type(4))) int            i32x4;

__device__ __forceinline__ unsigned short f2bf(float f) {
    union { float f; unsigned u; } v; v.f = f;
    unsigned r = v.u + 0x8000u + ((v.u >> 16) & 1u);   // RNE
    return (unsigned short)(r >> 16);
}

// out[m][o] = bias[o]; split-K blocks atomicAdd on top.
__global__ void init_out(const float* __restrict__ bias, float* __restrict__ out) {
    int idx = blockIdx.x * 256 + threadIdx.x;          // 2752 blocks exact
    out[idx] = bias[idx % OUT_F];
}

// Pre-swizzle x (64x4096 f32) into MFMA A-fragment order (bf16):
//   xf[((kb*4 + mt)*64 + lane)*8 + i] = x[mt*16 + (lane&15)][kb*32 + (lane>>4)*8 + i]
__global__ void prep_xfrag(const float* __restrict__ x, unsigned short* __restrict__ xf) {
    int kb   = blockIdx.x;            // 0..127
    int t    = threadIdx.x;           // 0..255
    int mt   = t >> 6;
    int lane = t & 63;
    int m  = mt * 16 + (lane & 15);
    int k0 = kb * 32 + (lane >> 4) * 8;
    const float* xp = x + m * IN_F + k0;
    f32x4 a = *(const f32x4*)(xp);
    f32x4 b = *(const f32x4*)(xp + 4);
    u16x8 v;
    v[0] = f2bf(a[0]); v[1] = f2bf(a[1]); v[2] = f2bf(a[2]); v[3] = f2bf(a[3]);
    v[4] = f2bf(b[0]); v[5] = f2bf(b[1]); v[6] = f2bf(b[2]); v[7] = f2bf(b[3]);
    *(u16x8*)(xf + (size_t)((kb * 4 + mt) * 64 + lane) * 8) = v;
}

// Grid: 688 o-tiles x 4 K-chunks = 2752 WGs of 256 (11008 waves, 43/CU).
// Within a WG, wave w takes kb windows {kc*32+w, +4, ..., +28} (stride-4
// interleave => each lane's j = k%128 set is FIXED: 8 scales, 1 packed zp reg).
// All 8 weight dwordx4 loads issued up front; afrag prefetch depth 2.
// No K-loop barriers. Epilogue: LDS-reduce 4 waves, one atomicAdd per element
// onto out pre-initialized with bias.
__global__ __launch_bounds__(256) void qlin_main(
    const int*   __restrict__ wq,
    const float* __restrict__ scale,
    const float* __restrict__ zp,
    const unsigned short* __restrict__ xf,
    float* __restrict__ out)
{
    __shared__ __align__(16) float lf[4096];     // 16 KB: epilogue reduce only

    const int t      = threadIdx.x;
    const int oi     = blockIdx.x >> 2;
    const int kc     = blockIdx.x & 3;           // K-chunk (1024 k = 512 dwords)
    const int o_base = oi * 16;
    const int wave   = t >> 6;
    const int lane   = t & 63;
    const int col16  = lane & 15;                // weight row within o-tile
    const int quad   = lane >> 4;
    const int row    = o_base + col16;

    // fixed j set for this lane: j = wave*32 + quad*8 + e, e=0..7
    float s[8];
    unsigned zpn;
    {
        const float* sp  = scale + (size_t)row * BLKQ + wave * 32 + quad * 8;
        const float* zpp = zp    + (size_t)row * BLKQ + wave * 32 + quad * 8;
        f32x4 s0 = *(const f32x4*)(sp);
        f32x4 s1 = *(const f32x4*)(sp + 4);
        f32x4 z0 = *(const f32x4*)(zpp);
        f32x4 z1 = *(const f32x4*)(zpp + 4);
        unsigned pk = 0;
        #pragma unroll
        for (int c = 0; c < 4; ++c) {
            s[c]     = s0[c];
            s[4 + c] = s1[c];
            pk |= ((unsigned)z0[c]) << (4 * c);
            pk |= ((unsigned)z1[c]) << (4 * (c + 4));
        }
        zpn = pk;
    }

    // weight base: dword = row*2048 + kc*512 + wave*16 + quad*4; step stride 64
    const int* wp = wq + (size_t)row * PKW + kc * 512 + wave * 16 + quad * 4;
    const s16x8* xfv = (const s16x8*)xf;
    const int kgb0 = kc * 32 + wave;             // global kb for step j: kgb0 + 4j

    // all 8 weight loads in flight immediately
    i32x4 wr[8];
    #pragma unroll
    for (int j = 0; j < 8; ++j) wr[j] = *(const i32x4*)(wp + j * 64);

    // afrag prefetch depth 2
    s16x8 ar[2][4];
    #pragma unroll
    for (int sl = 0; sl < 2; ++sl)
        #pragma unroll
        for (int mt = 0; mt < 4; ++mt)
            ar[sl][mt] = xfv[(size_t)(((kgb0 + 4 * sl) * 4 + mt) * 64 + lane)];

    f32x4 acc[4];
    #pragma unroll
    for (int mt = 0; mt < 4; ++mt) acc[mt] = (f32x4){0.f, 0.f, 0.f, 0.f};

    #pragma unroll
    for (int j = 0; j < 8; ++j) {
        // dequant wr[j] -> bf16 B fragment (k = quad*8 + e within window)
        u16x8 ub;
        #pragma unroll
        for (int e = 0; e < 8; ++e) {
            unsigned dw = (unsigned)wr[j][e >> 1];
            int wi = (e & 1) ? (int)(dw & 15u) : (int)((dw >> 4) & 15u);
            int zi = (int)((zpn >> (4 * e)) & 15u);
            ub[e] = f2bf((float)(wi - zi) * s[e]);
        }
        s16x8 bfrag;
        #pragma unroll
        for (int e = 0; e < 8; ++e) bfrag[e] = (short)ub[e];

        #pragma unroll
        for (int mt = 0; mt < 4; ++mt)
            acc[mt] = __builtin_amdgcn_mfma_f32_16x16x32_bf16(ar[j & 1][mt], bfrag, acc[mt], 0, 0, 0);

        // refill this afrag slot for step j+2
        if (j < 6) {
            #pragma unroll
            for (int mt = 0; mt < 4; ++mt)
                ar[j & 1][mt] = xfv[(size_t)(((kgb0 + 4 * (j + 2)) * 4 + mt) * 64 + lane)];
        }
    }

    // reduce the 4 waves via LDS, one atomicAdd per element
    #pragma unroll
    for (int mt = 0; mt < 4; ++mt) {
        #pragma unroll
        for (int r = 0; r < 4; ++r) {
            int m = mt * 16 + quad * 4 + r;      // C/D: col=lane&15, row=quad*4+reg
            lf[wave * 1024 + m * 16 + col16] = acc[mt][r];
        }
    }
    __syncthreads();
    #pragma unroll
    for (int p = 0; p < 4; ++p) {
        int e = p * 256 + t;
        int m = e >> 4, col = e & 15;
        float v = lf[e] + lf[1024 + e] + lf[2048 + e] + lf[3072 + e];
        atomicAdd(&out[(size_t)m * OUT_F + o_base + col], v);
    }
}

extern "C" void kernel_launch(void* const* d_in, const int* in_sizes, int n_in,
                              void* d_out, int out_size, void* d_ws, size_t ws_size,
                              hipStream_t stream) {
    const float* x     = (const float*)d_in[0];
    const int*   wq    = (const int*)d_in[1];
    const float* scale = (const float*)d_in[2];
    const float* zpv   = (const float*)d_in[3];
    const float* bias  = (const float*)d_in[4];
    float* out = (float*)d_out;
    unsigned short* xf = (unsigned short*)d_ws;   // 512 KB A-fragment buffer

    init_out<<<(64 * OUT_F) / 256, 256, 0, stream>>>(bias, out);
    prep_xfrag<<<128, 256, 0, stream>>>(x, xf);
    qlin_main<<<(OUT_F / 16) * 4, 256, 0, stream>>>(wq, scale, zpv, xf, out);
}

// Round 6
// 161.405 us; speedup vs baseline: 1.0658x; 1.0658x over previous
//
#include <hip/hip_runtime.h>

#define OUT_F 11008
#define IN_F  4096
#define PKW   2048   // int32 words per weight row (1 byte = 2 nibbles per word)
#define BLKQ  128

#define PAIR_STRIDE 1056            // 2 rows x 512B + 32B pad
#define BUF_BYTES   (16 * PAIR_STRIDE)  // 16896 B per round buffer

typedef __attribute__((ext_vector_type(8))) short          s16x8;
typedef __attribute__((ext_vector_type(8))) unsigned short u16x8;
typedef __attribute__((ext_vector_type(4))) float          f32x4;
typedef __attribute__((ext_vector_type(4))) int            i32x4;

__device__ __forceinline__ unsigned short f2bf(float f) {
    union { float f; unsigned u; } v; v.f = f;
    unsigned r = v.u + 0x8000u + ((v.u >> 16) & 1u);   // RNE
    return (unsigned short)(r >> 16);
}

// async global->LDS, 16B per lane; LDS dest = wave-uniform base + lane*16
__device__ __forceinline__ void async_copy16(const void* g, void* l) {
    __builtin_amdgcn_global_load_lds(
        (const __attribute__((address_space(1))) void*)g,
        (__attribute__((address_space(3))) void*)l,
        16, 0, 0);
}

// out[m][o] = bias[o]; split-K blocks atomicAdd on top.
__global__ void init_out(const float* __restrict__ bias, float* __restrict__ out) {
    int idx = blockIdx.x * 256 + threadIdx.x;          // 2752 blocks exact
    out[idx] = bias[idx % OUT_F];
}

// Pre-swizzle x (64x4096 f32) into MFMA A-fragment order (bf16):
//   xf[((kb*4 + mt)*64 + lane)*8 + i] = x[mt*16 + (lane&15)][kb*32 + (lane>>4)*8 + i]
__global__ void prep_xfrag(const float* __restrict__ x, unsigned short* __restrict__ xf) {
    int kb   = blockIdx.x;            // 0..127
    int t    = threadIdx.x;           // 0..255
    int mt   = t >> 6;
    int lane = t & 63;
    int m  = mt * 16 + (lane & 15);
    int k0 = kb * 32 + (lane >> 4) * 8;
    const float* xp = x + m * IN_F + k0;
    f32x4 a = *(const f32x4*)(xp);
    f32x4 b = *(const f32x4*)(xp + 4);
    u16x8 v;
    v[0] = f2bf(a[0]); v[1] = f2bf(a[1]); v[2] = f2bf(a[2]); v[3] = f2bf(a[3]);
    v[4] = f2bf(b[0]); v[5] = f2bf(b[1]); v[6] = f2bf(b[2]); v[7] = f2bf(b[3]);
    *(u16x8*)(xf + (size_t)((kb * 4 + mt) * 64 + lane) * 8) = v;
}

// Grid: 344 o-tiles(32 rows) x 2 K-halves = 688 WGs of 256.
// Per round (256 k): stage 32 rows x 512B raw dwords into LDS via
// global_load_lds (contiguous 1KB per instr, 4 instrs/wave), double-buffered,
// ONE barrier per round. Waves split windows by iw%4 => fixed j-set per lane.
// Consume: ds_read_b128 raw -> in-reg dequant -> bf16 bfrag -> MFMA.
__global__ __launch_bounds__(256) void qlin_main(
    const int*   __restrict__ wq,
    const float* __restrict__ scale,
    const float* __restrict__ zp,
    const unsigned short* __restrict__ xf,
    float* __restrict__ out)
{
    __shared__ __align__(16) unsigned char smem[2 * BUF_BYTES];  // 33792 B; reused as 32KB reduce

    const int t      = threadIdx.x;
    const int oi     = blockIdx.x >> 1;
    const int kc     = blockIdx.x & 1;           // K-half (2048 k = 1024 dwords)
    const int o_base = oi * 32;
    const int wave   = t >> 6;
    const int lane   = t & 63;
    const int col16  = lane & 15;
    const int quad   = lane >> 4;
    const int l5     = lane & 31;

    // dequant constants: j = wave*32 + quad*8 + e, for 2 o-half rows
    float s[2][8];
    unsigned zpn[2];
    #pragma unroll
    for (int oh = 0; oh < 2; ++oh) {
        int row = o_base + oh * 16 + col16;
        const float* sp  = scale + (size_t)row * BLKQ + wave * 32 + quad * 8;
        const float* zpp = zp    + (size_t)row * BLKQ + wave * 32 + quad * 8;
        f32x4 s0 = *(const f32x4*)(sp);
        f32x4 s1 = *(const f32x4*)(sp + 4);
        f32x4 z0 = *(const f32x4*)(zpp);
        f32x4 z1 = *(const f32x4*)(zpp + 4);
        unsigned pk = 0;
        #pragma unroll
        for (int c = 0; c < 4; ++c) {
            s[oh][c]     = s0[c];
            s[oh][4 + c] = s1[c];
            pk |= ((unsigned)z0[c]) << (4 * c);
            pk |= ((unsigned)z1[c]) << (4 * (c + 4));
        }
        zpn[oh] = pk;
    }

    const s16x8* xfv = (const s16x8*)xf;

    // stage round rr into buffer b: wave stages row-pairs p=4*wave+i,
    // rows 2p+(lane>>5), bytes (lane&31)*16 of the 512B round-chunk
    #define STAGE(rr, b) do {                                                   \
        const unsigned int* g0 = (const unsigned int*)wq                        \
            + (size_t)(o_base + wave * 8 + (lane >> 5)) * PKW                   \
            + kc * 1024 + (rr) * 128 + l5 * 4;                                  \
        unsigned char* lb = smem + (b) * BUF_BYTES + wave * 4 * PAIR_STRIDE;    \
        _Pragma("unroll")                                                       \
        for (int i_ = 0; i_ < 4; ++i_)                                          \
            async_copy16(g0 + (size_t)i_ * 2 * PKW, lb + i_ * PAIR_STRIDE);     \
    } while (0)

    f32x4 acc[2][4];
    #pragma unroll
    for (int oh = 0; oh < 2; ++oh)
        #pragma unroll
        for (int mt = 0; mt < 4; ++mt) acc[oh][mt] = (f32x4){0.f, 0.f, 0.f, 0.f};

    STAGE(0, 0);
    __syncthreads();

    for (int rr = 0; rr < 8; ++rr) {
        const unsigned char* buf = smem + (rr & 1) * BUF_BYTES;

        // 1) afrag loads first (so MFMA's vmcnt wait excludes the staging below)
        s16x8 ar[2][4];
        #pragma unroll
        for (int ii = 0; ii < 2; ++ii) {
            int kb = kc * 64 + rr * 8 + wave + 4 * ii;
            #pragma unroll
            for (int mt = 0; mt < 4; ++mt)
                ar[ii][mt] = xfv[(size_t)((kb * 4 + mt) * 64 + lane)];
        }

        // 2) stage next round (flies during compute, drained by end barrier)
        if (rr < 7) STAGE(rr + 1, (rr + 1) & 1);

        // 3) consume: 2 iw x 2 oh bfrags, 16 MFMAs
        #pragma unroll
        for (int ii = 0; ii < 2; ++ii) {
            int iw = wave + 4 * ii;
            #pragma unroll
            for (int oh = 0; oh < 2; ++oh) {
                int rowl = oh * 16 + col16;
                const unsigned char* baddr = buf + (rowl >> 1) * PAIR_STRIDE
                                           + (rowl & 1) * 512 + iw * 64 + quad * 16;
                i32x4 raw = *(const i32x4*)baddr;
                u16x8 ub;
                #pragma unroll
                for (int e = 0; e < 8; ++e) {
                    unsigned dw = (unsigned)raw[e >> 1];
                    int wi = (e & 1) ? (int)(dw & 15u) : (int)((dw >> 4) & 15u);
                    int zi = (int)((zpn[oh] >> (4 * e)) & 15u);
                    ub[e] = f2bf((float)(wi - zi) * s[oh][e]);
                }
                s16x8 bfrag;
                #pragma unroll
                for (int e = 0; e < 8; ++e) bfrag[e] = (short)ub[e];

                #pragma unroll
                for (int mt = 0; mt < 4; ++mt)
                    acc[oh][mt] = __builtin_amdgcn_mfma_f32_16x16x32_bf16(
                        ar[ii][mt], bfrag, acc[oh][mt], 0, 0, 0);
            }
        }

        __syncthreads();   // drains stage rr+1; syncs buf reads before overwrite
    }

    // epilogue: LDS-reduce the 4 waves, one atomicAdd per element
    float* lf = (float*)smem;
    #pragma unroll
    for (int oh = 0; oh < 2; ++oh)
        #pragma unroll
        for (int mt = 0; mt < 4; ++mt)
            #pragma unroll
            for (int r = 0; r < 4; ++r) {
                int m16 = quad * 4 + r;          // C/D: col=lane&15, row=quad*4+reg
                int e = ((oh * 4 + mt) * 16 + m16) * 16 + col16;
                lf[wave * 2048 + e] = acc[oh][mt][r];
            }
    __syncthreads();
    #pragma unroll
    for (int p = 0; p < 8; ++p) {
        int e = p * 256 + t;                     // 0..2047
        int col = e & 15, m16 = (e >> 4) & 15, c2 = e >> 8;
        int oh = c2 >> 2, mt = c2 & 3;
        int m = mt * 16 + m16;
        int o = o_base + oh * 16 + col;
        float v = lf[e] + lf[2048 + e] + lf[4096 + e] + lf[6144 + e];
        atomicAdd(&out[(size_t)m * OUT_F + o], v);
    }
    #undef STAGE
}

extern "C" void kernel_launch(void* const* d_in, const int* in_sizes, int n_in,
                              void* d_out, int out_size, void* d_ws, size_t ws_size,
                              hipStream_t stream) {
    const float* x     = (const float*)d_in[0];
    const int*   wq    = (const int*)d_in[1];
    const float* scale = (const float*)d_in[2];
    const float* zpv   = (const float*)d_in[3];
    const float* bias  = (const float*)d_in[4];
    float* out = (float*)d_out;
    unsigned short* xf = (unsigned short*)d_ws;   // 512 KB A-fragment buffer

    init_out<<<(64 * OUT_F) / 256, 256, 0, stream>>>(bias, out);
    prep_xfrag<<<128, 256, 0, stream>>>(x, xf);
    qlin_main<<<(OUT_F / 32) * 2, 256, 0, stream>>>(wq, scale, zpv, xf, out);
}